// Round 2
// baseline (5422.612 us; speedup 1.0000x reference)
//
#include <hip/hip_runtime.h>

#define N_NODES 100000
#define N_EDGES 3200000
#define N_GRAPHS 256
#define F_IN 128
#define CH 16

// ---------------- GEMM1: [N,128] @ [128,16] -> [N,16] ----------------
// Block = 256 threads, handles 16 nodes. x tile (16x128) + W1 (128x16) in LDS.
__global__ __launch_bounds__(256) void gemm1_kernel(const float* __restrict__ x,
                                                    const float* __restrict__ W1,
                                                    float* __restrict__ out) {
    __shared__ float xs[16 * 128];
    __shared__ float w1s[128 * 16];
    const int tid = threadIdx.x;
    const int nb = blockIdx.x * 16;
#pragma unroll
    for (int i = 0; i < 8; ++i) w1s[tid + i * 256] = W1[tid + i * 256];
    const float* xsrc = x + (size_t)nb * 128;
#pragma unroll
    for (int i = 0; i < 8; ++i) xs[tid + i * 256] = xsrc[tid + i * 256];
    __syncthreads();
    const int ln = tid >> 4, oc = tid & 15;
    float acc = 0.f;
#pragma unroll 8
    for (int k = 0; k < 128; ++k)
        acc = fmaf(xs[ln * 128 + k], w1s[k * 16 + oc], acc);
    out[(size_t)(nb + ln) * 16 + oc] = acc;
}

// ---------------- GEMM16: [N,16] @ [16,16] -> [N,16] ----------------
__global__ __launch_bounds__(256) void gemm16_kernel(const float* __restrict__ h,
                                                     const float* __restrict__ W,
                                                     float* __restrict__ out) {
    __shared__ float hs[256];
    __shared__ float wsm[256];
    const int tid = threadIdx.x;
    const int nb = blockIdx.x * 16;
    wsm[tid] = W[tid];
    hs[tid] = h[(size_t)nb * 16 + tid];
    __syncthreads();
    const int ln = tid >> 4, oc = tid & 15;
    float acc = 0.f;
#pragma unroll
    for (int k = 0; k < 16; ++k)
        acc = fmaf(hs[ln * 16 + k], wsm[k * 16 + oc], acc);
    out[(size_t)(nb + ln) * 16 + oc] = acc;
}

// ---------------- Edge scatter: agg[row] += h[col] * w ----------------
__global__ __launch_bounds__(256) void scatter_kernel(const float* __restrict__ h,
                                                      const float* __restrict__ w,
                                                      const int* __restrict__ row,
                                                      const int* __restrict__ col,
                                                      float* __restrict__ agg) {
    const int e = blockIdx.x * 256 + threadIdx.x;
    if (e >= N_EDGES) return;
    const int r = row[e], c = col[e];
    const float wt = w[e];
    const float4* hp = (const float4*)(h + (size_t)c * 16);
    float4 v0 = hp[0], v1 = hp[1], v2 = hp[2], v3 = hp[3];
    float* dst = agg + (size_t)r * 16;
    atomicAdd(dst + 0, v0.x * wt);
    atomicAdd(dst + 1, v0.y * wt);
    atomicAdd(dst + 2, v0.z * wt);
    atomicAdd(dst + 3, v0.w * wt);
    atomicAdd(dst + 4, v1.x * wt);
    atomicAdd(dst + 5, v1.y * wt);
    atomicAdd(dst + 6, v1.z * wt);
    atomicAdd(dst + 7, v1.w * wt);
    atomicAdd(dst + 8, v2.x * wt);
    atomicAdd(dst + 9, v2.y * wt);
    atomicAdd(dst + 10, v2.z * wt);
    atomicAdd(dst + 11, v2.w * wt);
    atomicAdd(dst + 12, v3.x * wt);
    atomicAdd(dst + 13, v3.y * wt);
    atomicAdd(dst + 14, v3.z * wt);
    atomicAdd(dst + 15, v3.w * wt);
}

// ---------------- ELU(a + b) in place ----------------
__global__ __launch_bounds__(256) void elubias_kernel(float* __restrict__ a,
                                                      const float* __restrict__ b) {
    __shared__ float bs[16];
    if (threadIdx.x < 16) bs[threadIdx.x] = b[threadIdx.x];
    __syncthreads();
    const int total = N_NODES * 16;
    for (int i = blockIdx.x * 256 + threadIdx.x; i < total; i += gridDim.x * 256) {
        float v = a[i] + bs[i & 15];
        a[i] = v > 0.f ? v : expm1f(v);
    }
}

// ---------------- Pool: pooled[seg[n]] += h[n]  (seg sorted) ----------------
#define POOL_NODES 1024
__global__ __launch_bounds__(256) void pool_kernel(const float* __restrict__ h,
                                                   const int* __restrict__ seg,
                                                   float* __restrict__ pooled) {
    __shared__ float lp[N_GRAPHS * 16];
    const int tid = threadIdx.x;
    for (int i = tid; i < N_GRAPHS * 16; i += 256) lp[i] = 0.f;
    __syncthreads();
    const int base = blockIdx.x * POOL_NODES;
    const int lim = min(base + POOL_NODES, N_NODES);
    for (int idx = base * 16 + tid; idx < lim * 16; idx += 256) {
        const int node = idx >> 4;
        const int ch = idx & 15;
        atomicAdd(&lp[seg[node] * 16 + ch], h[idx]);
    }
    __syncthreads();
    const int s0 = seg[base];
    const int s1 = seg[lim - 1];
    const int cnt = (s1 - s0 + 1) * 16;
    for (int j = tid; j < cnt; j += 256) {
        atomicAdd(&pooled[s0 * 16 + j], lp[s0 * 16 + j]);
    }
}

// ---------------- Head: sigmoid(relu(pooled@Wd2+bd2)@Wd3+bd3) ----------------
__global__ __launch_bounds__(256) void head_kernel(const float* __restrict__ pooled,
                                                   const float* __restrict__ Wd2,
                                                   const float* __restrict__ bd2,
                                                   const float* __restrict__ Wd3,
                                                   const float* __restrict__ bd3,
                                                   float* __restrict__ out) {
    __shared__ float w2[256], w3[32], b2s[16], b3s[2];
    const int tid = threadIdx.x;
    w2[tid] = Wd2[tid];
    if (tid < 32) w3[tid] = Wd3[tid];
    if (tid < 16) b2s[tid] = bd2[tid];
    if (tid < 2) b3s[tid] = bd3[tid];
    __syncthreads();
    const int g = tid;  // 256 graphs == 256 threads
    float p[16];
#pragma unroll
    for (int k = 0; k < 16; ++k) p[k] = pooled[g * 16 + k];
    float t[16];
#pragma unroll
    for (int j = 0; j < 16; ++j) {
        float acc = b2s[j];
#pragma unroll
        for (int k = 0; k < 16; ++k) acc = fmaf(p[k], w2[k * 16 + j], acc);
        t[j] = acc > 0.f ? acc : 0.f;
    }
#pragma unroll
    for (int m = 0; m < 2; ++m) {
        float acc = b3s[m];
#pragma unroll
        for (int j = 0; j < 16; ++j) acc = fmaf(t[j], w3[j * 2 + m], acc);
        out[g * 2 + m] = 1.f / (1.f + expf(-acc));
    }
}

extern "C" void kernel_launch(void* const* d_in, const int* in_sizes, int n_in,
                              void* d_out, int out_size, void* d_ws, size_t ws_size,
                              hipStream_t stream) {
    const float* x   = (const float*)d_in[0];
    const float* ew  = (const float*)d_in[1];
    const float* W1  = (const float*)d_in[2];
    const float* b1  = (const float*)d_in[3];
    const float* W2  = (const float*)d_in[4];
    const float* b2  = (const float*)d_in[5];
    const float* Wd2 = (const float*)d_in[6];
    const float* bd2 = (const float*)d_in[7];
    const float* Wd3 = (const float*)d_in[8];
    const float* bd3 = (const float*)d_in[9];
    const int* row   = (const int*)d_in[10];
    const int* col   = (const int*)d_in[11];
    const int* seg   = (const int*)d_in[12];
    float* out = (float*)d_out;

    float* A = (float*)d_ws;                  // [N,16] scratch
    float* B = A + (size_t)N_NODES * 16;      // [N,16] scratch
    float* pooled = B + (size_t)N_NODES * 16; // [256,16]

    const size_t h_bytes = (size_t)N_NODES * 16 * sizeof(float);
    const int edge_blocks = (N_EDGES + 255) / 256;

    // Layer 1: h1 = elu(A_w @ (x@W1) + b1)
    gemm1_kernel<<<N_NODES / 16, 256, 0, stream>>>(x, W1, A);
    hipMemsetAsync(B, 0, h_bytes, stream);
    scatter_kernel<<<edge_blocks, 256, 0, stream>>>(A, ew, row, col, B);
    elubias_kernel<<<2048, 256, 0, stream>>>(B, b1);

    // Layer 2: h2 = elu(A_w @ (h1@W2) + b2)
    gemm16_kernel<<<N_NODES / 16, 256, 0, stream>>>(B, W2, A);
    hipMemsetAsync(B, 0, h_bytes, stream);
    scatter_kernel<<<edge_blocks, 256, 0, stream>>>(A, ew, row, col, B);
    elubias_kernel<<<2048, 256, 0, stream>>>(B, b2);

    // Pool + head
    hipMemsetAsync(pooled, 0, N_GRAPHS * 16 * sizeof(float), stream);
    pool_kernel<<<(N_NODES + POOL_NODES - 1) / POOL_NODES, 256, 0, stream>>>(B, seg, pooled);
    head_kernel<<<1, 256, 0, stream>>>(pooled, Wd2, bd2, Wd3, bd3, out);
}

// Round 3
// 529.422 us; speedup vs baseline: 10.2425x; 10.2425x over previous
//
#include <hip/hip_runtime.h>

#define N_NODES 100000
#define N_EDGES 3200000
#define N_GRAPHS 256
#define F_IN 128
#define CH 16

// ---------------- GEMM1: [N,128] @ [128,16] -> [N,16] ----------------
__global__ __launch_bounds__(256) void gemm1_kernel(const float* __restrict__ x,
                                                    const float* __restrict__ W1,
                                                    float* __restrict__ out) {
    __shared__ float xs[16 * 128];
    __shared__ float w1s[128 * 16];
    const int tid = threadIdx.x;
    const int nb = blockIdx.x * 16;
#pragma unroll
    for (int i = 0; i < 8; ++i) w1s[tid + i * 256] = W1[tid + i * 256];
    const float* xsrc = x + (size_t)nb * 128;
#pragma unroll
    for (int i = 0; i < 8; ++i) xs[tid + i * 256] = xsrc[tid + i * 256];
    __syncthreads();
    const int ln = tid >> 4, oc = tid & 15;
    float acc = 0.f;
#pragma unroll 8
    for (int k = 0; k < 128; ++k)
        acc = fmaf(xs[ln * 128 + k], w1s[k * 16 + oc], acc);
    out[(size_t)(nb + ln) * 16 + oc] = acc;
}

// ---------------- GEMM16: [N,16] @ [16,16] -> [N,16] ----------------
__global__ __launch_bounds__(256) void gemm16_kernel(const float* __restrict__ h,
                                                     const float* __restrict__ W,
                                                     float* __restrict__ out) {
    __shared__ float hs[256];
    __shared__ float wsm[256];
    const int tid = threadIdx.x;
    const int nb = blockIdx.x * 16;
    wsm[tid] = W[tid];
    hs[tid] = h[(size_t)nb * 16 + tid];
    __syncthreads();
    const int ln = tid >> 4, oc = tid & 15;
    float acc = 0.f;
#pragma unroll
    for (int k = 0; k < 16; ++k)
        acc = fmaf(hs[ln * 16 + k], wsm[k * 16 + oc], acc);
    out[(size_t)(nb + ln) * 16 + oc] = acc;
}

// ---------------- Edge scatter: agg[row] += h[col] * w ----------------
// 16 threads per edge (one per channel): each wave = 4 edges; the 16 lanes
// of an edge hit 16 consecutive dwords of one 64B line -> atomics merge into
// line-granular requests instead of 64 random lines per instruction.
__global__ __launch_bounds__(256) void scatter_kernel(const float* __restrict__ h,
                                                      const float* __restrict__ w,
                                                      const int* __restrict__ row,
                                                      const int* __restrict__ col,
                                                      float* __restrict__ agg) {
    const long long t = (long long)blockIdx.x * 256 + threadIdx.x;
    const int e = (int)(t >> 4);   // edge index
    const int ch = (int)(t & 15);  // channel
    const int r = row[e], c = col[e];
    const float wt = w[e];
    const float v = h[(size_t)c * 16 + ch] * wt;
    atomicAdd(agg + (size_t)r * 16 + ch, v);
}

// ---------------- ELU(a + b) in place ----------------
__global__ __launch_bounds__(256) void elubias_kernel(float* __restrict__ a,
                                                      const float* __restrict__ b) {
    __shared__ float bs[16];
    if (threadIdx.x < 16) bs[threadIdx.x] = b[threadIdx.x];
    __syncthreads();
    const int total = N_NODES * 16;
    for (int i = blockIdx.x * 256 + threadIdx.x; i < total; i += gridDim.x * 256) {
        float v = a[i] + bs[i & 15];
        a[i] = v > 0.f ? v : expm1f(v);
    }
}

// ---------------- Pool: pooled[seg[n]] += h[n]  (seg sorted) ----------------
#define POOL_NODES 1024
__global__ __launch_bounds__(256) void pool_kernel(const float* __restrict__ h,
                                                   const int* __restrict__ seg,
                                                   float* __restrict__ pooled) {
    __shared__ float lp[N_GRAPHS * 16];
    const int tid = threadIdx.x;
    for (int i = tid; i < N_GRAPHS * 16; i += 256) lp[i] = 0.f;
    __syncthreads();
    const int base = blockIdx.x * POOL_NODES;
    const int lim = min(base + POOL_NODES, N_NODES);
    for (int idx = base * 16 + tid; idx < lim * 16; idx += 256) {
        const int node = idx >> 4;
        const int ch = idx & 15;
        atomicAdd(&lp[seg[node] * 16 + ch], h[idx]);
    }
    __syncthreads();
    const int s0 = seg[base];
    const int s1 = seg[lim - 1];
    const int cnt = (s1 - s0 + 1) * 16;
    for (int j = tid; j < cnt; j += 256) {
        atomicAdd(&pooled[s0 * 16 + j], lp[s0 * 16 + j]);
    }
}

// ---------------- Head: sigmoid(relu(pooled@Wd2+bd2)@Wd3+bd3) ----------------
__global__ __launch_bounds__(256) void head_kernel(const float* __restrict__ pooled,
                                                   const float* __restrict__ Wd2,
                                                   const float* __restrict__ bd2,
                                                   const float* __restrict__ Wd3,
                                                   const float* __restrict__ bd3,
                                                   float* __restrict__ out) {
    __shared__ float w2[256], w3[32], b2s[16], b3s[2];
    const int tid = threadIdx.x;
    w2[tid] = Wd2[tid];
    if (tid < 32) w3[tid] = Wd3[tid];
    if (tid < 16) b2s[tid] = bd2[tid];
    if (tid < 2) b3s[tid] = bd3[tid];
    __syncthreads();
    const int g = tid;  // 256 graphs == 256 threads
    float p[16];
#pragma unroll
    for (int k = 0; k < 16; ++k) p[k] = pooled[g * 16 + k];
    float t[16];
#pragma unroll
    for (int j = 0; j < 16; ++j) {
        float acc = b2s[j];
#pragma unroll
        for (int k = 0; k < 16; ++k) acc = fmaf(p[k], w2[k * 16 + j], acc);
        t[j] = acc > 0.f ? acc : 0.f;
    }
#pragma unroll
    for (int m = 0; m < 2; ++m) {
        float acc = b3s[m];
#pragma unroll
        for (int j = 0; j < 16; ++j) acc = fmaf(t[j], w3[j * 2 + m], acc);
        out[g * 2 + m] = 1.f / (1.f + expf(-acc));
    }
}

extern "C" void kernel_launch(void* const* d_in, const int* in_sizes, int n_in,
                              void* d_out, int out_size, void* d_ws, size_t ws_size,
                              hipStream_t stream) {
    const float* x   = (const float*)d_in[0];
    const float* ew  = (const float*)d_in[1];
    const float* W1  = (const float*)d_in[2];
    const float* b1  = (const float*)d_in[3];
    const float* W2  = (const float*)d_in[4];
    const float* b2  = (const float*)d_in[5];
    const float* Wd2 = (const float*)d_in[6];
    const float* bd2 = (const float*)d_in[7];
    const float* Wd3 = (const float*)d_in[8];
    const float* bd3 = (const float*)d_in[9];
    const int* row   = (const int*)d_in[10];
    const int* col   = (const int*)d_in[11];
    const int* seg   = (const int*)d_in[12];
    float* out = (float*)d_out;

    float* A = (float*)d_ws;                  // [N,16] scratch
    float* B = A + (size_t)N_NODES * 16;      // [N,16] scratch
    float* pooled = B + (size_t)N_NODES * 16; // [256,16]

    const size_t h_bytes = (size_t)N_NODES * 16 * sizeof(float);
    const int scatter_blocks = (int)(((long long)N_EDGES * 16) / 256);  // 200000 exact

    // Layer 1: h1 = elu(A_w @ (x@W1) + b1)
    gemm1_kernel<<<N_NODES / 16, 256, 0, stream>>>(x, W1, A);
    hipMemsetAsync(B, 0, h_bytes, stream);
    scatter_kernel<<<scatter_blocks, 256, 0, stream>>>(A, ew, row, col, B);
    elubias_kernel<<<2048, 256, 0, stream>>>(B, b1);

    // Layer 2: h2 = elu(A_w @ (h1@W2) + b2)
    gemm16_kernel<<<N_NODES / 16, 256, 0, stream>>>(B, W2, A);
    hipMemsetAsync(B, 0, h_bytes, stream);
    scatter_kernel<<<scatter_blocks, 256, 0, stream>>>(A, ew, row, col, B);
    elubias_kernel<<<2048, 256, 0, stream>>>(B, b2);

    // Pool + head
    hipMemsetAsync(pooled, 0, N_GRAPHS * 16 * sizeof(float), stream);
    pool_kernel<<<(N_NODES + POOL_NODES - 1) / POOL_NODES, 256, 0, stream>>>(B, seg, pooled);
    head_kernel<<<1, 256, 0, stream>>>(pooled, Wd2, bd2, Wd3, bd3, out);
}